// Round 4
// baseline (66.162 us; speedup 1.0000x reference)
//
#include <hip/hip_runtime.h>
#include <math.h>

#define B_SZ   65536
#define RATE   5
#define NNEG   (B_SZ * RATE)
#define NC     100
#define NE     2048
#define GN     16
#define GP     5
#define EPSC   1e-4f

#define NBN    320      // neg blocks, 1024 elems each (320*1024 = 327680)
#define NBP    64       // pos blocks, 1024 elems each (64*1024 = 65536)
#define NBT    256      // tail blocks, 256 elems each

__device__ __forceinline__ float wave_sumf(float v) {
    #pragma unroll
    for (int off = 32; off > 0; off >>= 1) v += __shfl_down(v, off, 64);
    return v;
}
__device__ __forceinline__ float clip01(float x) {
    return fminf(fmaxf(x, EPSC), 1.0f);
}

// ---------------- K1: per-row argmax + max-softmax confidence ----------------
// One LANE per row, zero cross-lane ops. Output packed {conf, argmax} float2.
__global__ __launch_bounds__(256, 2) void k_rowstats(
    const float* __restrict__ pred_to, const float* __restrict__ pred_from,
    float2* __restrict__ pk_to, float2* __restrict__ pk_from,
    unsigned int* __restrict__ counter)
{
    if (blockIdx.x == 0 && threadIdx.x == 0) *counter = 0u;   // reset tail flag
    int i = blockIdx.x * blockDim.x + threadIdx.x;            // 0 .. 2*B_SZ-1
    const float* row = (i < B_SZ) ? pred_to + (size_t)i * NC
                                  : pred_from + (size_t)(i - B_SZ) * NC;
    const float4* r4 = (const float4*)row;
    float4 v[25];
    #pragma unroll
    for (int t = 0; t < 25; ++t) v[t] = r4[t];

    float m = -INFINITY;
    #pragma unroll
    for (int t = 0; t < 25; ++t)
        m = fmaxf(m, fmaxf(fmaxf(v[t].x, v[t].y), fmaxf(v[t].z, v[t].w)));

    int bi = NC;
    float s = 0.0f;
    #pragma unroll
    for (int t = 0; t < 25; ++t) {
        float e0 = v[t].x, e1 = v[t].y, e2 = v[t].z, e3 = v[t].w;
        if (e0 == m) bi = min(bi, 4 * t + 0);
        if (e1 == m) bi = min(bi, 4 * t + 1);
        if (e2 == m) bi = min(bi, 4 * t + 2);
        if (e3 == m) bi = min(bi, 4 * t + 3);
        s += expf(e0 - m) + expf(e1 - m) + expf(e2 - m) + expf(e3 - m);
    }
    float2 pk = make_float2(1.0f / s, __uint_as_float((unsigned)bi));
    if (i < B_SZ) pk_to[i] = pk; else pk_from[i - B_SZ] = pk;
}

// ---------------- K2: fused negative-sample + positive/grid pass -------------
__global__ __launch_bounds__(256) void k_negpos(
    const int* __restrict__ perm,
    const float2* __restrict__ emb_to, const float2* __restrict__ emb_from,
    const float2* __restrict__ pk_to, const float2* __restrict__ pk_from,
    const int* __restrict__ idx_to, const int* __restrict__ idx_from,
    const float* __restrict__ probs,
    const int* __restrict__ error_conf,
    const float2* __restrict__ neg_grid, const float2* __restrict__ pos_grid,
    const float* __restrict__ dist_list,
    float* __restrict__ pneg, float* __restrict__ ppos)
{
    __shared__ float sr[6][4];
    int w = threadIdx.x >> 6, lane = threadIdx.x & 63;
    if (blockIdx.x < NBN) {
        // ---- negative-sample path: 4 elems/thread ----
        const unsigned long long* pkt = (const unsigned long long*)pk_to;
        const unsigned long long* pkf = (const unsigned long long*)pk_from;
        int base = blockIdx.x * 1024 + threadIdx.x;
        float ce = 0.f, cnt = 0.f, ds = 0.f;
        #pragma unroll
        for (int k = 0; k < 4; ++k) {
            int i = base + k * 256;
            unsigned jt = (unsigned)i / RATE;
            unsigned jf = (unsigned)perm[i] / RATE;
            // same ⟺ (conf equal && argmax equal) ⟺ packed 8B equal
            if (pkt[jt] != pkf[jf]) {
                float2 et = emb_to[jt], ef = emb_from[jf];
                float dx = et.x - ef.x, dy = et.y - ef.y;
                float d2 = dx * dx + dy * dy;
                float om = d2 / (1.0f + d2);          // 1 - q
                ce  += -logf(clip01(om));
                cnt += 1.0f;
                ds  += sqrtf(d2);
            }
        }
        ce = wave_sumf(ce); cnt = wave_sumf(cnt); ds = wave_sumf(ds);
        if (lane == 0) { sr[0][w] = ce; sr[1][w] = cnt; sr[2][w] = ds; }
        __syncthreads();
        if (threadIdx.x < 3) {
            int j = threadIdx.x;
            pneg[blockIdx.x * 3 + j] = sr[j][0] + sr[j][1] + sr[j][2] + sr[j][3];
        }
    } else {
        // ---- positive + confidence-grid path: 4 elems/thread ----
        __shared__ int ec[NE];
        int blk = blockIdx.x - NBN;
        for (int t = threadIdx.x; t < NE; t += 256) ec[t] = error_conf[t];
        __syncthreads();

        float v0 = 0.f, v1 = 0.f, v2 = 0.f, v3 = 0.f, v4 = 0.f, v5 = 0.f;
        for (int k = 0; k < 4; ++k) {
            int i = blk * 1024 + threadIdx.x + k * 256;
            float2 et = emb_to[i], ef = emb_from[i];
            float dx = et.x - ef.x, dy = et.y - ef.y;
            float d2 = dx * dx + dy * dy;
            v1 += sqrtf(d2);
            float p = probs[i];
            float q  = 1.0f / (1.0f + d2);
            float om = d2 / (1.0f + d2);
            v0 += -p * logf(clip01(q)) - (1.0f - p) * logf(clip01(om));

            int vt = idx_to[i];
            int lo = 0, hi = NE;
            while (lo < hi) { int mid = (lo + hi) >> 1; if (ec[mid] < vt) lo = mid + 1; else hi = mid; }
            int gt = (lo < NE) ? lo : NE - 1;
            bool hit_t = (ec[gt] == vt);

            int vf = idx_from[i];
            lo = 0; hi = NE;
            while (lo < hi) { int mid = (lo + hi) >> 1; if (ec[mid] < vf) lo = mid + 1; else hi = mid; }
            int gf = (lo < NE) ? lo : NE - 1;
            bool hit_f = (ec[gf] == vf);

            if (hit_t) {
                v4 += 1.0f;
                float sa = 0.f;
                #pragma unroll
                for (int k2 = 0; k2 < GN; ++k2) {
                    float2 g = neg_grid[gt * GN + k2];
                    float ax = et.x - g.x, ay = et.y - g.y;      // embedding_to
                    float dd = ax * ax + ay * ay;
                    sa += -logf(clip01(dd / (1.0f + dd)));
                }
                v0 += sa;
                if (dist_list[gt] < 0.5f) {
                    v2 += 1.0f;
                    float s2 = 0.f;
                    #pragma unroll
                    for (int k2 = 0; k2 < GP; ++k2) {
                        float2 g = pos_grid[gt * GP + k2];
                        float ax = ef.x - g.x, ay = ef.y - g.y;  // embedding_from (per reference)
                        float dd = ax * ax + ay * ay;
                        s2 += -logf(clip01(1.0f / (1.0f + dd)));
                    }
                    v0 += s2;
                }
            }
            if (hit_f) {
                v5 += 1.0f;
                float sa = 0.f;
                #pragma unroll
                for (int k2 = 0; k2 < GN; ++k2) {
                    float2 g = neg_grid[gf * GN + k2];
                    float ax = ef.x - g.x, ay = ef.y - g.y;      // embedding_from
                    float dd = ax * ax + ay * ay;
                    sa += -logf(clip01(dd / (1.0f + dd)));
                }
                v0 += sa;
                if (dist_list[gf] < 1.0f) {
                    v3 += 1.0f;
                    float s2 = 0.f;
                    #pragma unroll
                    for (int k2 = 0; k2 < GP; ++k2) {
                        float2 g = pos_grid[gf * GP + k2];
                        float ax = ef.x - g.x, ay = ef.y - g.y;
                        float dd = ax * ax + ay * ay;
                        s2 += -logf(clip01(1.0f / (1.0f + dd)));
                    }
                    v0 += s2;
                }
            }
        }
        float vv[6] = {v0, v1, v2, v3, v4, v5};
        #pragma unroll
        for (int j = 0; j < 6; ++j) {
            float r = wave_sumf(vv[j]);
            if (lane == 0) sr[j][w] = r;
        }
        __syncthreads();
        if (threadIdx.x < 6) {
            int j = threadIdx.x;
            ppos[blk * 6 + j] = sr[j][0] + sr[j][1] + sr[j][2] + sr[j][3];
        }
    }
}

// ---------------- K3: tail — redundant reduce + margin + last-block final ----
__global__ __launch_bounds__(256) void k_tail(
    const float2* __restrict__ emb_to, const float2* __restrict__ emb_from,
    const float* __restrict__ probs,
    const float2* __restrict__ pk_to, const float2* __restrict__ pk_from,
    const float* __restrict__ pneg, const float* __restrict__ ppos,
    float* __restrict__ pmar, unsigned int* __restrict__ counter,
    float* __restrict__ out)
{
    __shared__ float sr[8][4];
    __shared__ float tot[8];
    __shared__ bool islast;
    int w = threadIdx.x >> 6, lane = threadIdx.x & 63;

    // phase 1: every block redundantly reduces the partials (tiny, L2-hot)
    float s[8] = {0, 0, 0, 0, 0, 0, 0, 0};
    // 0 ce | 1 neg_cnt | 2 neg_dsum | 3 pos_dsum | 4 cwt | 5 cwf | 6 cmt | 7 cmf
    for (int b = threadIdx.x; b < NBN; b += 256) {
        s[0] += pneg[b * 3 + 0]; s[1] += pneg[b * 3 + 1]; s[2] += pneg[b * 3 + 2];
    }
    if (threadIdx.x < NBP) {
        int b = threadIdx.x;
        s[0] += ppos[b * 6 + 0]; s[3] += ppos[b * 6 + 1]; s[4] += ppos[b * 6 + 2];
        s[5] += ppos[b * 6 + 3]; s[6] += ppos[b * 6 + 4]; s[7] += ppos[b * 6 + 5];
    }
    #pragma unroll
    for (int j = 0; j < 8; ++j) {
        float r = wave_sumf(s[j]);
        if (lane == 0) sr[j][w] = r;
    }
    __syncthreads();
    if (threadIdx.x < 8) {
        int j = threadIdx.x;
        tot[j] = sr[j][0] + sr[j][1] + sr[j][2] + sr[j][3];
    }
    __syncthreads();
    float pos_mean = tot[3] * (1.0f / (float)B_SZ);
    float neg_mean = tot[2] / fmaxf(tot[1], 1.0f);

    // phase 2: margin slice
    int i = blockIdx.x * 256 + threadIdx.x;
    float2 et = emb_to[i], ef = emb_from[i];
    float2 at = pk_to[i], af = pk_from[i];
    float dx = et.x - ef.x, dy = et.y - ef.y;
    float d = sqrtf(dx * dx + dy * dy);
    float p = probs[i];
    float bm = pos_mean + (neg_mean - pos_mean) * (1.0f - p);
    float mg = (at.y == af.y) ? 0.0f : bm;       // .y holds argmax bits, exact compare
    float ms = fmaxf(mg - d, 0.0f);
    ms = wave_sumf(ms);
    if (lane == 0) sr[0][w] = ms;
    __syncthreads();

    // phase 3: publish partial, last block finalizes
    if (threadIdx.x == 0) {
        pmar[blockIdx.x] = sr[0][0] + sr[0][1] + sr[0][2] + sr[0][3];
        __threadfence();
        unsigned old = atomicAdd(counter, 1u);
        islast = (old == NBT - 1);
    }
    __syncthreads();
    if (islast) {
        __threadfence();
        float v = pmar[threadIdx.x];   // NBT == 256, one per thread
        v = wave_sumf(v);
        if (lane == 0) sr[1][w] = v;
        __syncthreads();
        if (threadIdx.x == 0) {
            float msum = sr[1][0] + sr[1][1] + sr[1][2] + sr[1][3];
            float total_cnt = (float)B_SZ + (float)GP * (tot[4] + tot[5])
                            + tot[1] + (float)GN * (tot[6] + tot[7]);
            float umap = tot[0] / fmaxf(total_cnt, 1.0f);
            if (isnan(umap)) umap = 0.0f;
            float ml = msum * (1.0f / (float)B_SZ);
            if (isnan(ml)) ml = 0.0f;
            out[0] = umap;
            out[1] = ml;
            out[2] = umap + ml;
        }
    }
}

extern "C" void kernel_launch(void* const* d_in, const int* in_sizes, int n_in,
                              void* d_out, int out_size, void* d_ws, size_t ws_size,
                              hipStream_t stream)
{
    const int*   edge_to_idx   = (const int*)d_in[0];
    const int*   edge_from_idx = (const int*)d_in[1];
    const float* embedding_to  = (const float*)d_in[2];
    const float* embedding_from= (const float*)d_in[3];
    const float* probs         = (const float*)d_in[4];
    const float* pred_to       = (const float*)d_in[5];
    const float* pred_from     = (const float*)d_in[6];
    const int*   perm          = (const int*)d_in[7];
    const int*   error_conf    = (const int*)d_in[8];
    const float* neg_grid      = (const float*)d_in[9];
    const float* pos_grid      = (const float*)d_in[10];
    const float* dist_list     = (const float*)d_in[11];

    char* ws = (char*)d_ws;
    unsigned int* counter = (unsigned int*)ws;
    float2*       pk_to   = (float2*)(ws + 256);
    float2*       pk_from = pk_to + B_SZ;
    float*        pneg    = (float*)(pk_from + B_SZ);   // NBN*3
    float*        ppos    = pneg + NBN * 3;             // NBP*6
    float*        pmar    = ppos + NBP * 6;             // NBT

    k_rowstats<<<(2 * B_SZ) / 256, 256, 0, stream>>>(
        pred_to, pred_from, pk_to, pk_from, counter);

    k_negpos<<<NBN + NBP, 256, 0, stream>>>(
        perm, (const float2*)embedding_to, (const float2*)embedding_from,
        pk_to, pk_from,
        edge_to_idx, edge_from_idx, probs, error_conf,
        (const float2*)neg_grid, (const float2*)pos_grid, dist_list,
        pneg, ppos);

    k_tail<<<NBT, 256, 0, stream>>>(
        (const float2*)embedding_to, (const float2*)embedding_from,
        probs, pk_to, pk_from, pneg, ppos, pmar, counter, (float*)d_out);
}

// Round 5
// 43.889 us; speedup vs baseline: 1.5075x; 1.5075x over previous
//
#include <hip/hip_runtime.h>
#include <math.h>

#define B_SZ   65536
#define RATE   5
#define NNEG   (B_SZ * RATE)
#define NC     100
#define NE     2048
#define GN     16
#define GP     5
#define EPSC   1e-4f

#define NBN    1280     // neg blocks, 256 elems each (1 elem/thread)
#define NBP    256      // pos blocks, 256 elems each
#define NBT    256      // tail blocks, 256 elems each

__device__ __forceinline__ float wave_sumf(float v) {
    #pragma unroll
    for (int off = 32; off > 0; off >>= 1) v += __shfl_down(v, off, 64);
    return v;
}
__device__ __forceinline__ float clip01(float x) {
    return fminf(fmaxf(x, EPSC), 1.0f);
}

// ---------------- K1: per-row argmax + max-softmax confidence ----------------
// One LANE per row, zero cross-lane ops. Output packed {conf, argmax} float2.
__global__ __launch_bounds__(256, 2) void k_rowstats(
    const float* __restrict__ pred_to, const float* __restrict__ pred_from,
    float2* __restrict__ pk_to, float2* __restrict__ pk_from,
    unsigned int* __restrict__ counter)
{
    if (blockIdx.x == 0 && threadIdx.x == 0) *counter = 0u;   // reset tail flag
    int i = blockIdx.x * blockDim.x + threadIdx.x;            // 0 .. 2*B_SZ-1
    const float* row = (i < B_SZ) ? pred_to + (size_t)i * NC
                                  : pred_from + (size_t)(i - B_SZ) * NC;
    const float4* r4 = (const float4*)row;
    float4 v[25];
    #pragma unroll
    for (int t = 0; t < 25; ++t) v[t] = r4[t];

    float m = -INFINITY;
    #pragma unroll
    for (int t = 0; t < 25; ++t)
        m = fmaxf(m, fmaxf(fmaxf(v[t].x, v[t].y), fmaxf(v[t].z, v[t].w)));

    int bi = NC;
    float s = 0.0f;
    #pragma unroll
    for (int t = 0; t < 25; ++t) {
        float e0 = v[t].x, e1 = v[t].y, e2 = v[t].z, e3 = v[t].w;
        if (e0 == m) bi = min(bi, 4 * t + 0);
        if (e1 == m) bi = min(bi, 4 * t + 1);
        if (e2 == m) bi = min(bi, 4 * t + 2);
        if (e3 == m) bi = min(bi, 4 * t + 3);
        s += expf(e0 - m) + expf(e1 - m) + expf(e2 - m) + expf(e3 - m);
    }
    float2 pk = make_float2(1.0f / s, __uint_as_float((unsigned)bi));
    if (i < B_SZ) pk_to[i] = pk; else pk_from[i - B_SZ] = pk;
}

// ---------------- K2: fused negative-sample + positive/grid pass -------------
__global__ __launch_bounds__(256) void k_negpos(
    const int* __restrict__ perm,
    const float2* __restrict__ emb_to, const float2* __restrict__ emb_from,
    const float2* __restrict__ pk_to, const float2* __restrict__ pk_from,
    const int* __restrict__ idx_to, const int* __restrict__ idx_from,
    const float* __restrict__ probs,
    const int* __restrict__ error_conf,
    const float2* __restrict__ neg_grid, const float2* __restrict__ pos_grid,
    const float* __restrict__ dist_list,
    float* __restrict__ pneg, float* __restrict__ ppos)
{
    __shared__ float sr[6][4];
    int w = threadIdx.x >> 6, lane = threadIdx.x & 63;
    if (blockIdx.x < NBN) {
        // ---- negative-sample path: 1 elem/thread, max TLP ----
        const unsigned long long* pkt = (const unsigned long long*)pk_to;
        const unsigned long long* pkf = (const unsigned long long*)pk_from;
        int i = blockIdx.x * 256 + threadIdx.x;
        float ce = 0.f, cnt = 0.f, ds = 0.f;
        {
            unsigned jt = (unsigned)i / RATE;
            unsigned jf = (unsigned)perm[i] / RATE;
            // same ⟺ (conf equal && argmax equal) ⟺ packed 8B equal
            if (pkt[jt] != pkf[jf]) {
                float2 et = emb_to[jt], ef = emb_from[jf];
                float dx = et.x - ef.x, dy = et.y - ef.y;
                float d2 = dx * dx + dy * dy;
                float om = d2 / (1.0f + d2);          // 1 - q
                ce  = -logf(clip01(om));
                cnt = 1.0f;
                ds  = sqrtf(d2);
            }
        }
        ce = wave_sumf(ce); cnt = wave_sumf(cnt); ds = wave_sumf(ds);
        if (lane == 0) { sr[0][w] = ce; sr[1][w] = cnt; sr[2][w] = ds; }
        __syncthreads();
        if (threadIdx.x < 3) {
            int j = threadIdx.x;
            pneg[blockIdx.x * 3 + j] = sr[j][0] + sr[j][1] + sr[j][2] + sr[j][3];
        }
    } else {
        // ---- positive + confidence-grid path: 1 elem/thread ----
        __shared__ int ec[NE];
        int blk = blockIdx.x - NBN;
        for (int t = threadIdx.x; t < NE; t += 256) ec[t] = error_conf[t];
        __syncthreads();

        float v0 = 0.f, v1 = 0.f, v2 = 0.f, v3 = 0.f, v4 = 0.f, v5 = 0.f;
        {
            int i = blk * 256 + threadIdx.x;
            float2 et = emb_to[i], ef = emb_from[i];
            float dx = et.x - ef.x, dy = et.y - ef.y;
            float d2 = dx * dx + dy * dy;
            v1 = sqrtf(d2);
            float p = probs[i];
            float q  = 1.0f / (1.0f + d2);
            float om = d2 / (1.0f + d2);
            v0 = -p * logf(clip01(q)) - (1.0f - p) * logf(clip01(om));

            int vt = idx_to[i];
            int lo = 0, hi = NE;
            while (lo < hi) { int mid = (lo + hi) >> 1; if (ec[mid] < vt) lo = mid + 1; else hi = mid; }
            int gt = (lo < NE) ? lo : NE - 1;
            bool hit_t = (ec[gt] == vt);

            int vf = idx_from[i];
            lo = 0; hi = NE;
            while (lo < hi) { int mid = (lo + hi) >> 1; if (ec[mid] < vf) lo = mid + 1; else hi = mid; }
            int gf = (lo < NE) ? lo : NE - 1;
            bool hit_f = (ec[gf] == vf);

            if (hit_t) {
                v4 = 1.0f;
                float sa = 0.f;
                #pragma unroll
                for (int k2 = 0; k2 < GN; ++k2) {
                    float2 g = neg_grid[gt * GN + k2];
                    float ax = et.x - g.x, ay = et.y - g.y;      // embedding_to
                    float dd = ax * ax + ay * ay;
                    sa += -logf(clip01(dd / (1.0f + dd)));
                }
                v0 += sa;
                if (dist_list[gt] < 0.5f) {
                    v2 = 1.0f;
                    float s2 = 0.f;
                    #pragma unroll
                    for (int k2 = 0; k2 < GP; ++k2) {
                        float2 g = pos_grid[gt * GP + k2];
                        float ax = ef.x - g.x, ay = ef.y - g.y;  // embedding_from (per reference)
                        float dd = ax * ax + ay * ay;
                        s2 += -logf(clip01(1.0f / (1.0f + dd)));
                    }
                    v0 += s2;
                }
            }
            if (hit_f) {
                v5 = 1.0f;
                float sa = 0.f;
                #pragma unroll
                for (int k2 = 0; k2 < GN; ++k2) {
                    float2 g = neg_grid[gf * GN + k2];
                    float ax = ef.x - g.x, ay = ef.y - g.y;      // embedding_from
                    float dd = ax * ax + ay * ay;
                    sa += -logf(clip01(dd / (1.0f + dd)));
                }
                v0 += sa;
                if (dist_list[gf] < 1.0f) {
                    v3 = 1.0f;
                    float s2 = 0.f;
                    #pragma unroll
                    for (int k2 = 0; k2 < GP; ++k2) {
                        float2 g = pos_grid[gf * GP + k2];
                        float ax = ef.x - g.x, ay = ef.y - g.y;
                        float dd = ax * ax + ay * ay;
                        s2 += -logf(clip01(1.0f / (1.0f + dd)));
                    }
                    v0 += s2;
                }
            }
        }
        float vv[6] = {v0, v1, v2, v3, v4, v5};
        #pragma unroll
        for (int j = 0; j < 6; ++j) {
            float r = wave_sumf(vv[j]);
            if (lane == 0) sr[j][w] = r;
        }
        __syncthreads();
        if (threadIdx.x < 6) {
            int j = threadIdx.x;
            ppos[blk * 6 + j] = sr[j][0] + sr[j][1] + sr[j][2] + sr[j][3];
        }
    }
}

// ---------------- K3: tail — redundant reduce + margin + last-block final ----
__global__ __launch_bounds__(256) void k_tail(
    const float2* __restrict__ emb_to, const float2* __restrict__ emb_from,
    const float* __restrict__ probs,
    const float2* __restrict__ pk_to, const float2* __restrict__ pk_from,
    const float* __restrict__ pneg, const float* __restrict__ ppos,
    float* __restrict__ pmar, unsigned int* __restrict__ counter,
    float* __restrict__ out)
{
    __shared__ float sr[8][4];
    __shared__ float tot[8];
    __shared__ bool islast;
    int w = threadIdx.x >> 6, lane = threadIdx.x & 63;

    // phase 1: every block redundantly reduces the partials (tiny, L2-hot)
    float s[8] = {0, 0, 0, 0, 0, 0, 0, 0};
    // 0 ce | 1 neg_cnt | 2 neg_dsum | 3 pos_dsum | 4 cwt | 5 cwf | 6 cmt | 7 cmf
    for (int b = threadIdx.x; b < NBN; b += 256) {
        s[0] += pneg[b * 3 + 0]; s[1] += pneg[b * 3 + 1]; s[2] += pneg[b * 3 + 2];
    }
    for (int b = threadIdx.x; b < NBP; b += 256) {
        s[0] += ppos[b * 6 + 0]; s[3] += ppos[b * 6 + 1]; s[4] += ppos[b * 6 + 2];
        s[5] += ppos[b * 6 + 3]; s[6] += ppos[b * 6 + 4]; s[7] += ppos[b * 6 + 5];
    }
    #pragma unroll
    for (int j = 0; j < 8; ++j) {
        float r = wave_sumf(s[j]);
        if (lane == 0) sr[j][w] = r;
    }
    __syncthreads();
    if (threadIdx.x < 8) {
        int j = threadIdx.x;
        tot[j] = sr[j][0] + sr[j][1] + sr[j][2] + sr[j][3];
    }
    __syncthreads();
    float pos_mean = tot[3] * (1.0f / (float)B_SZ);
    float neg_mean = tot[2] / fmaxf(tot[1], 1.0f);

    // phase 2: margin slice
    int i = blockIdx.x * 256 + threadIdx.x;
    float2 et = emb_to[i], ef = emb_from[i];
    float2 at = pk_to[i], af = pk_from[i];
    float dx = et.x - ef.x, dy = et.y - ef.y;
    float d = sqrtf(dx * dx + dy * dy);
    float p = probs[i];
    float bm = pos_mean + (neg_mean - pos_mean) * (1.0f - p);
    float mg = (at.y == af.y) ? 0.0f : bm;       // .y holds argmax bits, exact compare
    float ms = fmaxf(mg - d, 0.0f);
    ms = wave_sumf(ms);
    if (lane == 0) sr[0][w] = ms;
    __syncthreads();

    // phase 3: publish partial, last block finalizes
    if (threadIdx.x == 0) {
        pmar[blockIdx.x] = sr[0][0] + sr[0][1] + sr[0][2] + sr[0][3];
        __threadfence();
        unsigned old = atomicAdd(counter, 1u);
        islast = (old == NBT - 1);
    }
    __syncthreads();
    if (islast) {
        __threadfence();
        float v = pmar[threadIdx.x];   // NBT == 256, one per thread
        v = wave_sumf(v);
        if (lane == 0) sr[1][w] = v;
        __syncthreads();
        if (threadIdx.x == 0) {
            float msum = sr[1][0] + sr[1][1] + sr[1][2] + sr[1][3];
            float total_cnt = (float)B_SZ + (float)GP * (tot[4] + tot[5])
                            + tot[1] + (float)GN * (tot[6] + tot[7]);
            float umap = tot[0] / fmaxf(total_cnt, 1.0f);
            if (isnan(umap)) umap = 0.0f;
            float ml = msum * (1.0f / (float)B_SZ);
            if (isnan(ml)) ml = 0.0f;
            out[0] = umap;
            out[1] = ml;
            out[2] = umap + ml;
        }
    }
}

extern "C" void kernel_launch(void* const* d_in, const int* in_sizes, int n_in,
                              void* d_out, int out_size, void* d_ws, size_t ws_size,
                              hipStream_t stream)
{
    const int*   edge_to_idx   = (const int*)d_in[0];
    const int*   edge_from_idx = (const int*)d_in[1];
    const float* embedding_to  = (const float*)d_in[2];
    const float* embedding_from= (const float*)d_in[3];
    const float* probs         = (const float*)d_in[4];
    const float* pred_to       = (const float*)d_in[5];
    const float* pred_from     = (const float*)d_in[6];
    const int*   perm          = (const int*)d_in[7];
    const int*   error_conf    = (const int*)d_in[8];
    const float* neg_grid      = (const float*)d_in[9];
    const float* pos_grid      = (const float*)d_in[10];
    const float* dist_list     = (const float*)d_in[11];

    char* ws = (char*)d_ws;
    unsigned int* counter = (unsigned int*)ws;
    float2*       pk_to   = (float2*)(ws + 256);
    float2*       pk_from = pk_to + B_SZ;
    float*        pneg    = (float*)(pk_from + B_SZ);   // NBN*3
    float*        ppos    = pneg + NBN * 3;             // NBP*6
    float*        pmar    = ppos + NBP * 6;             // NBT

    k_rowstats<<<(2 * B_SZ) / 256, 256, 0, stream>>>(
        pred_to, pred_from, pk_to, pk_from, counter);

    k_negpos<<<NBN + NBP, 256, 0, stream>>>(
        perm, (const float2*)embedding_to, (const float2*)embedding_from,
        pk_to, pk_from,
        edge_to_idx, edge_from_idx, probs, error_conf,
        (const float2*)neg_grid, (const float2*)pos_grid, dist_list,
        pneg, ppos);

    k_tail<<<NBT, 256, 0, stream>>>(
        (const float2*)embedding_to, (const float2*)embedding_from,
        probs, pk_to, pk_from, pneg, ppos, pmar, counter, (float*)d_out);
}